// Round 8
// baseline (3256.165 us; speedup 1.0000x reference)
//
#include <hip/hip_runtime.h>
#include <hip/hip_bf16.h>

// Problem constants: B=32, T=512, D=768, H=256, K=32
// Outputs: d_out[0] = loss (f32), d_out[1 + b*512 + t] = preds as float.

#define NB 32
#define NT 512
#define ND 768
#define NH 256
#define NK 32

// ---------------------------------------------------------------------------
// K1: SGEMM  C[16384][2048] = x[16384][768] @ [W_ih_f | W_ih_b]^T
// 128x128 tile, 8x8 per thread, BK=16, fp32, double-buffered (verified R6).
// ---------------------------------------------------------------------------
__global__ __launch_bounds__(256) void k_sgemm(const float* __restrict__ A,
                                               const float* __restrict__ Wf,
                                               const float* __restrict__ Wb,
                                               float* __restrict__ C) {
    __shared__ float As[2][16][132];
    __shared__ float Bs[2][16][132];
    const int tid = threadIdx.x;
    const int bx = blockIdx.x;   // n tile: 0..15
    const int by = blockIdx.y;   // m tile: 0..127
    const int tx = tid & 15, ty = tid >> 4;
    const int sm = tid >> 2;           // 0..63
    const int sk = (tid & 3) * 4;      // 0,4,8,12
    float acc[8][8];
#pragma unroll
    for (int i = 0; i < 8; ++i)
#pragma unroll
        for (int j = 0; j < 8; ++j) acc[i][j] = 0.f;

    const float* Arow0 = A + (size_t)(by * 128 + sm) * ND + sk;
    const float* Arow1 = A + (size_t)(by * 128 + 64 + sm) * ND + sk;
    const int gn0 = bx * 128 + sm, gn1 = gn0 + 64;
    const float* W0 = (gn0 < 1024) ? (Wf + (size_t)gn0 * ND + sk) : (Wb + (size_t)(gn0 - 1024) * ND + sk);
    const float* W1 = (gn1 < 1024) ? (Wf + (size_t)gn1 * ND + sk) : (Wb + (size_t)(gn1 - 1024) * ND + sk);

    {
        float4 a0 = *(const float4*)(Arow0);
        float4 a1 = *(const float4*)(Arow1);
        float4 w0 = *(const float4*)(W0);
        float4 w1 = *(const float4*)(W1);
        As[0][sk + 0][sm] = a0.x; As[0][sk + 1][sm] = a0.y; As[0][sk + 2][sm] = a0.z; As[0][sk + 3][sm] = a0.w;
        As[0][sk + 0][64 + sm] = a1.x; As[0][sk + 1][64 + sm] = a1.y; As[0][sk + 2][64 + sm] = a1.z; As[0][sk + 3][64 + sm] = a1.w;
        Bs[0][sk + 0][sm] = w0.x; Bs[0][sk + 1][sm] = w0.y; Bs[0][sk + 2][sm] = w0.z; Bs[0][sk + 3][sm] = w0.w;
        Bs[0][sk + 0][64 + sm] = w1.x; Bs[0][sk + 1][64 + sm] = w1.y; Bs[0][sk + 2][64 + sm] = w1.z; Bs[0][sk + 3][64 + sm] = w1.w;
    }
    __syncthreads();

    int cur = 0;
    for (int k0 = 0; k0 < ND; k0 += 16) {
        const bool more = (k0 + 16) < ND;
        float4 na0, na1, nw0, nw1;
        if (more) {
            na0 = *(const float4*)(Arow0 + k0 + 16);
            na1 = *(const float4*)(Arow1 + k0 + 16);
            nw0 = *(const float4*)(W0 + k0 + 16);
            nw1 = *(const float4*)(W1 + k0 + 16);
        }
#pragma unroll
        for (int kk = 0; kk < 16; ++kk) {
            float a[8], b[8];
            *(float4*)&a[0] = *(const float4*)&As[cur][kk][ty * 4];
            *(float4*)&a[4] = *(const float4*)&As[cur][kk][64 + ty * 4];
            *(float4*)&b[0] = *(const float4*)&Bs[cur][kk][tx * 4];
            *(float4*)&b[4] = *(const float4*)&Bs[cur][kk][64 + tx * 4];
#pragma unroll
            for (int i = 0; i < 8; ++i)
#pragma unroll
                for (int j = 0; j < 8; ++j)
                    acc[i][j] = fmaf(a[i], b[j], acc[i][j]);
        }
        if (more) {
            const int nxt = cur ^ 1;
            As[nxt][sk + 0][sm] = na0.x; As[nxt][sk + 1][sm] = na0.y; As[nxt][sk + 2][sm] = na0.z; As[nxt][sk + 3][sm] = na0.w;
            As[nxt][sk + 0][64 + sm] = na1.x; As[nxt][sk + 1][64 + sm] = na1.y; As[nxt][sk + 2][64 + sm] = na1.z; As[nxt][sk + 3][64 + sm] = na1.w;
            Bs[nxt][sk + 0][sm] = nw0.x; Bs[nxt][sk + 1][sm] = nw0.y; Bs[nxt][sk + 2][sm] = nw0.z; Bs[nxt][sk + 3][sm] = nw0.w;
            Bs[nxt][sk + 0][64 + sm] = nw1.x; Bs[nxt][sk + 1][64 + sm] = nw1.y; Bs[nxt][sk + 2][64 + sm] = nw1.z; Bs[nxt][sk + 3][64 + sm] = nw1.w;
            __syncthreads();
            cur = nxt;
        }
    }
#pragma unroll
    for (int i = 0; i < 8; ++i) {
        int m = by * 128 + ((i < 4) ? (ty * 4 + i) : (64 + ty * 4 + (i - 4)));
        float* Crow = C + (size_t)m * 2048 + bx * 128;
        *(float4*)(Crow + tx * 4)      = make_float4(acc[i][0], acc[i][1], acc[i][2], acc[i][3]);
        *(float4*)(Crow + 64 + tx * 4) = make_float4(acc[i][4], acc[i][5], acc[i][6], acc[i][7]);
    }
}

// ---------------------------------------------------------------------------
// K1.5: transpose W_hh into Wt4[(dir*256 + k)*256 + j] =
//   {W[0*256+j][k], W[1*256+j][k], W[2*256+j][k], W[3*256+j][k]}
// ---------------------------------------------------------------------------
__global__ __launch_bounds__(256) void k_wt4(const float* __restrict__ Whf,
                                             const float* __restrict__ Whb,
                                             float4* __restrict__ Wt4) {
    int gid = blockIdx.x * 256 + threadIdx.x;
    if (gid >= 131072) return;
    int dir = gid >> 16;
    int k   = (gid >> 8) & 255;
    int j   = gid & 255;
    const float* W = dir ? Whb : Whf;
    Wt4[gid] = make_float4(W[(size_t)(0 * 256 + j) * 256 + k],
                           W[(size_t)(1 * 256 + j) * 256 + k],
                           W[(size_t)(2 * 256 + j) * 256 + k],
                           W[(size_t)(3 * 256 + j) * 256 + k]);
}

// ---------------------------------------------------------------------------
// K2: LSTM recurrence v4 — W FULLY RESIDENT (regs + LDS), no per-step W
// re-streaming.  Theory: R2/R6's ~2 us/step == L2 re-read of the spilled
// 256-float wreg (VGPR_Count 152 << 256 needed). Fix: j-split-8.
//
// Grid 512 x 256, __launch_bounds__(256,2) => VGPR<=256, LDS 68.6KB/block
// => EXACTLY 2 blocks/CU resident (137KB<=160KB), so all 512 blocks are
// co-resident: poll protocol liveness guaranteed by construction.
// (R7 resubmission: container infra failed twice; kernel unchanged except
// poll guard 2^24 -> 2^22. Deadlock-free by residency; a tripped guard
// publishes a non-sentinel NaN so downstream never spins long.)
//
// Block (g = bid&63 -> batch b=g&31, dir=g>>5; s = bid>>6 in [0,8)) owns
// j-slice j0=s*32. Thread (j=tid>>3 in [0,32), kq=tid&7) covers k in
// [32kq,32kq+32): 64 floats in VGPRs (16 float4) + 64 floats in LDS
// wlds[u][tid] (own-column reads, lane-consecutive 16B, conflict-free).
// Per wave: poll 4 h-dims/lane (packed 8B agent atomics, sentinel
// 0xFFFFFFFF), distribute via wave-private hsh row (stride-36 padding =>
// 8 kq-groups hit disjoint bank quads), FMA, 3-round shfl_xor butterfly
// over kq, C+bias injected once per gate via masked pre-butterfly add.
// All 8 kq lanes replicate gates/c/h bitwise-identically; kq==0 stores h.
// No __syncthreads in the t-loop at all.
// ---------------------------------------------------------------------------
__device__ __forceinline__ float sigm(float x) { return 1.f / (1.f + expf(-x)); }

__global__ __launch_bounds__(256, 2) void k_lstm5(const float* __restrict__ C,
                                                  const float4* __restrict__ Wt4,
                                                  const float* __restrict__ b_f,
                                                  const float* __restrict__ b_b,
                                                  const int* __restrict__ lengths,
                                                  float* __restrict__ h_f,
                                                  float* __restrict__ h_b) {
    __shared__ float4 wlds[16][256];   // 64 KB: W k-sub [16,32) per thread
    __shared__ float hsh[4][288];      // per-wave h(t-1); kq-region r at r*36
    const int tid = threadIdx.x;
    const int g = blockIdx.x & 63, s = blockIdx.x >> 6;
    const int b = g & 31, dir = g >> 5;
    const int j0 = s * 32;
    const float* bias = dir ? b_b : b_f;
    float* hdir = dir ? h_b : h_f;

    const int j = tid >> 3;       // 0..31
    const int kq = tid & 7;       // 0..7
    const int w = tid >> 6;       // wave id
    const int lane = tid & 63;

    float4 wreg[16];
    {
        const float4* wb = Wt4 + ((size_t)dir * 256 + 32 * kq) * 256 + j0 + j;
#pragma unroll
        for (int u = 0; u < 16; ++u) wreg[u] = wb[(size_t)u * 256];
#pragma unroll
        for (int u = 0; u < 16; ++u) wlds[u][tid] = wb[(size_t)(16 + u) * 256];
    }
    float preBias = (kq < 4) ? bias[kq * 256 + j0 + j] : 0.f;
    const int mylen = lengths[b];
    float creg = 0.f;
    __syncthreads();

    for (int t = 0; t < NT; ++t) {
        // C value for (gate kq, dim j0+j): one dword per lane (kq<4), issued
        // before the poll so its latency hides under it.
        float preS = 0.f;
        if (kq < 4) {
            int src_t = t;
            if (dir) src_t = (t < mylen) ? (mylen - 1 - t) : t;
            preS = C[(size_t)(b * 512 + src_t) * 2048 + dir * 1024 + kq * 256 + j0 + j];
        }
        float4 acc = make_float4(0.f, 0.f, 0.f, 0.f);
        if (t > 0) {
            // wave-autonomous poll: lane owns dims [4*lane, 4*lane+4)
            const float* hp = hdir + ((size_t)b * 512 + (t - 1)) * 256 + 4 * lane;
            unsigned long long u0, u1;
            int guard = 0;
            for (;;) {
                u0 = __hip_atomic_load((const unsigned long long*)hp,
                                       __ATOMIC_RELAXED, __HIP_MEMORY_SCOPE_AGENT);
                u1 = __hip_atomic_load((const unsigned long long*)(hp + 2),
                                       __ATOMIC_RELAXED, __HIP_MEMORY_SCOPE_AGENT);
                if ((unsigned)(u0 & 0xFFFFFFFFu) != 0xFFFFFFFFu &&
                    (unsigned)(u0 >> 32)        != 0xFFFFFFFFu &&
                    (unsigned)(u1 & 0xFFFFFFFFu) != 0xFFFFFFFFu &&
                    (unsigned)(u1 >> 32)        != 0xFFFFFFFFu) break;
                if (++guard > (1 << 22)) break;   // liveness valve
            }
            // distribute in wave-private hsh row (region = lane>>3, off 4b)
            float* dst = &hsh[w][(lane >> 3) * 36 + ((4 * lane) & 31)];
            *(float4*)dst = make_float4(
                __uint_as_float((unsigned)(u0 & 0xFFFFFFFFu)),
                __uint_as_float((unsigned)(u0 >> 32)),
                __uint_as_float((unsigned)(u1 & 0xFFFFFFFFu)),
                __uint_as_float((unsigned)(u1 >> 32)));
            asm volatile("s_waitcnt lgkmcnt(0)" ::: "memory");
            __builtin_amdgcn_sched_barrier(0);
            const float* hbp = &hsh[w][kq * 36];
            // k-sub [0,16): W in VGPRs
#pragma unroll
            for (int c = 0; c < 4; ++c) {
                float ha[4];
                *(float4*)ha = *(const float4*)(hbp + 4 * c);
#pragma unroll
                for (int i = 0; i < 4; ++i) {
                    float4 wv = wreg[c * 4 + i];
                    acc.x = fmaf(wv.x, ha[i], acc.x);
                    acc.y = fmaf(wv.y, ha[i], acc.y);
                    acc.z = fmaf(wv.z, ha[i], acc.z);
                    acc.w = fmaf(wv.w, ha[i], acc.w);
                }
            }
            // k-sub [16,32): W in LDS (own-column, conflict-free)
#pragma unroll
            for (int c = 0; c < 4; ++c) {
                float ha[4];
                *(float4*)ha = *(const float4*)(hbp + 16 + 4 * c);
#pragma unroll
                for (int i = 0; i < 4; ++i) {
                    float4 wv = wlds[c * 4 + i][tid];
                    acc.x = fmaf(wv.x, ha[i], acc.x);
                    acc.y = fmaf(wv.y, ha[i], acc.y);
                    acc.z = fmaf(wv.z, ha[i], acc.z);
                    acc.w = fmaf(wv.w, ha[i], acc.w);
                }
            }
        }
        // inject C + bias exactly once per gate (lane kq adds to component kq)
        float add = preS + preBias;
        acc.x += (kq == 0) ? add : 0.f;
        acc.y += (kq == 1) ? add : 0.f;
        acc.z += (kq == 2) ? add : 0.f;
        acc.w += (kq == 3) ? add : 0.f;
        // butterfly over kq (lane bits 0..2): all 8 lanes end bitwise-identical
#pragma unroll
        for (int off = 1; off <= 4; off <<= 1) {
            acc.x += __shfl_xor(acc.x, off);
            acc.y += __shfl_xor(acc.y, off);
            acc.z += __shfl_xor(acc.z, off);
            acc.w += __shfl_xor(acc.w, off);
        }
        float ig = sigm(acc.x), fg = sigm(acc.y), gt = tanhf(acc.z), og = sigm(acc.w);
        creg = fg * creg + ig * gt;
        float hn = og * tanhf(creg);
        if (kq == 0)
            __hip_atomic_store(hdir + ((size_t)b * 512 + t) * 256 + j0 + j, hn,
                               __ATOMIC_RELAXED, __HIP_MEMORY_SCOPE_AGENT);
        // write-once h slots: the store IS the publication.
    }
}

// ---------------------------------------------------------------------------
// K3: emissions  em[b][t][k] = hcat . W_clf[k] + b_clf[k]
// ---------------------------------------------------------------------------
__global__ __launch_bounds__(256) void k_em(const float* __restrict__ hf,
                                            const float* __restrict__ hb,
                                            const float* __restrict__ Wclf,
                                            const float* __restrict__ bclf,
                                            const int* __restrict__ lengths,
                                            float* __restrict__ em) {
    extern __shared__ float4 wc4[];   // [128][32]: wc4[jq*32+ko] = Wclf[ko][4jq..+3]
    const int tid = threadIdx.x;
    for (int idx = tid; idx < 4096; idx += 256) {
        int jq = idx >> 5, ko = idx & 31;
        wc4[idx] = *(const float4*)(Wclf + (size_t)ko * 512 + jq * 4);
    }
    __syncthreads();
    const int r = tid >> 5, ko = tid & 31;
    const int m = blockIdx.x * 8 + r;
    const int b = m >> 9, t = m & 511;
    const int len = lengths[b];
    const int rev = (t < len) ? (len - 1 - t) : t;
    const float* hfr = hf + (size_t)m * 256;
    const float* hbr = hb + (size_t)(b * 512 + rev) * 256;
    float acc = bclf[ko];
#pragma unroll 4
    for (int jq = 0; jq < 64; ++jq) {
        float4 h4 = *(const float4*)(hfr + jq * 4);
        float4 ww = wc4[jq * 32 + ko];
        acc += h4.x * ww.x + h4.y * ww.y + h4.z * ww.z + h4.w * ww.w;
    }
#pragma unroll 4
    for (int jq = 0; jq < 64; ++jq) {
        float4 h4 = *(const float4*)(hbr + jq * 4);
        float4 ww = wc4[(64 + jq) * 32 + ko];
        acc += h4.x * ww.x + h4.y * ww.y + h4.z * ww.z + h4.w * ww.w;
    }
    em[(size_t)m * 32 + ko] = acc;
}

// ---------------------------------------------------------------------------
// K4: CRF forward (logZ, num) and Viterbi (+backtrace).
// ---------------------------------------------------------------------------
__global__ __launch_bounds__(64) void k_crfvit(const float* __restrict__ em,
                                               const int* __restrict__ targets,
                                               const int* __restrict__ lengths,
                                               const float* __restrict__ start_t,
                                               const float* __restrict__ end_t,
                                               const float* __restrict__ trans,
                                               float* __restrict__ numv,
                                               float* __restrict__ logZv,
                                               float* __restrict__ out) {
    __shared__ float trans_s[32][33];
    __shared__ float vec[32];
    __shared__ unsigned char hist[511 * 32];
    const int tid = threadIdx.x;
    const int b = blockIdx.x & 31;
    const int mode = blockIdx.x >> 5;
    for (int idx = tid; idx < 1024; idx += 64) trans_s[idx >> 5][idx & 31] = trans[idx];
    const int len = lengths[b];
    const float* emb = em + (size_t)b * 512 * 32;
    const int k = tid & 31, half = tid >> 5;
    if (tid < 32) vec[tid] = start_t[tid] + emb[tid];
    __syncthreads();

    if (mode == 0) {
        for (int t = 1; t < NT; ++t) {
            bool mv = t < len;
            int kp0 = half * 16;
            float m = -1e30f;
#pragma unroll 4
            for (int i = 0; i < 16; ++i)
                m = fmaxf(m, vec[kp0 + i] + trans_s[kp0 + i][k]);
            float m2 = fmaxf(m, __shfl_xor(m, 32));
            float ssum = 0.f;
#pragma unroll 4
            for (int i = 0; i < 16; ++i)
                ssum += __expf(vec[kp0 + i] + trans_s[kp0 + i][k] - m2);
            ssum += __shfl_xor(ssum, 32);
            float anew = m2 + __logf(ssum) + emb[t * 32 + k];
            __syncthreads();
            if (half == 0 && mv) vec[k] = anew;
            __syncthreads();
        }
        float val = (tid < 32) ? vec[tid] + end_t[tid] : -1e30f;
        float m = val;
#pragma unroll
        for (int off = 32; off >= 1; off >>= 1) m = fmaxf(m, __shfl_xor(m, off));
        float e = (tid < 32) ? __expf(val - m) : 0.f;
#pragma unroll
        for (int off = 32; off >= 1; off >>= 1) e += __shfl_xor(e, off);
        if (tid == 0) logZv[b] = m + __logf(e);
        // numerator
        const int* tg = targets + b * 512;
        float partial = 0.f;
        for (int t = 1 + tid; t < NT; t += 64) {
            if (t < len) {
                int y0 = tg[t - 1], y1 = tg[t];
                partial += trans_s[y0][y1] + emb[t * 32 + y1];
            }
        }
#pragma unroll
        for (int off = 32; off >= 1; off >>= 1) partial += __shfl_xor(partial, off);
        if (tid == 0) {
            int y00 = tg[0];
            int yl = tg[len - 1];
            numv[b] = partial + start_t[y00] + emb[y00] + end_t[yl];
        }
    } else {
        for (int t = 1; t < NT; ++t) {
            bool mv = t < len;
            int kp0 = half * 16;
            float e = emb[t * 32 + k];
            float m = -1e30f; int mi = kp0;
#pragma unroll 4
            for (int i = 0; i < 16; ++i) {
                float v = (vec[kp0 + i] + trans_s[kp0 + i][k]) + e;
                if (v > m) { m = v; mi = kp0 + i; }
            }
            float mo = __shfl_xor(m, 32);
            int io = __shfl_xor(mi, 32);
            float mlow = half ? mo : m;   int ilow = half ? io : mi;
            float mhigh = half ? m : mo;  int ihigh = half ? mi : io;
            float bm; int bi;
            if (mhigh > mlow) { bm = mhigh; bi = ihigh; } else { bm = mlow; bi = ilow; }
            __syncthreads();
            if (half == 0) {
                hist[(t - 1) * 32 + k] = (unsigned char)(mv ? bi : k);
                if (mv) vec[k] = bm;
            }
            __syncthreads();
        }
        float val = (tid < 32) ? vec[tid] + end_t[tid] : -1e30f;
        int idx = (tid < 32) ? tid : 63;
#pragma unroll
        for (int off = 32; off >= 1; off >>= 1) {
            float vo = __shfl_xor(val, off);
            int io = __shfl_xor(idx, off);
            if (vo > val || (vo == val && io < idx)) { val = vo; idx = io; }
        }
        int cur = idx;
        float* ob = out + 1 + (size_t)b * 512;
        if (tid == 0) ob[511] = (511 < len) ? (float)cur : 0.f;
        for (int t2 = 510; t2 >= 0; --t2) {
            cur = hist[t2 * 32 + cur];
            if (tid == 0) ob[t2] = (t2 < len) ? (float)cur : 0.f;
        }
    }
}

// ---------------------------------------------------------------------------
// K5: loss = -mean(num - logZ)
// ---------------------------------------------------------------------------
__global__ __launch_bounds__(64) void k_loss(const float* __restrict__ numv,
                                             const float* __restrict__ logZv,
                                             float* __restrict__ out) {
    int tid = threadIdx.x;
    float v = (tid < 32) ? (logZv[tid] - numv[tid]) : 0.f;
#pragma unroll
    for (int off = 32; off >= 1; off >>= 1) v += __shfl_xor(v, off);
    if (tid == 0) out[0] = v / 32.f;
}

// ---------------------------------------------------------------------------
extern "C" void kernel_launch(void* const* d_in, const int* in_sizes, int n_in,
                              void* d_out, int out_size, void* d_ws, size_t ws_size,
                              hipStream_t stream) {
    const float* x       = (const float*)d_in[0];
    const int*   lengths = (const int*)d_in[1];
    // d_in[2] = mask (recomputed from lengths)
    const int*   targets = (const int*)d_in[3];
    const float* W_ih_f  = (const float*)d_in[4];
    const float* W_hh_f  = (const float*)d_in[5];
    const float* b_f     = (const float*)d_in[6];
    const float* W_ih_b  = (const float*)d_in[7];
    const float* W_hh_b  = (const float*)d_in[8];
    const float* b_b     = (const float*)d_in[9];
    const float* W_clf   = (const float*)d_in[10];
    const float* b_clf   = (const float*)d_in[11];
    const float* start_t = (const float*)d_in[12];
    const float* end_t   = (const float*)d_in[13];
    const float* trans   = (const float*)d_in[14];
    float* out = (float*)d_out;
    float* ws = (float*)d_ws;

    float* C     = ws;                                   // 16384*2048
    float* h_f   = C + (size_t)16384 * 2048;             // 32*512*256
    float* h_b   = h_f + (size_t)32 * 512 * 256;         // 32*512*256
    float* em    = h_b + (size_t)32 * 512 * 256;         // 32*512*32
    float4* Wt4  = (float4*)(em + (size_t)32 * 512 * 32);// 131072 float4
    float* numv  = (float*)(Wt4 + 131072);               // 32
    float* logZv = numv + 32;                            // 32

    // Re-poison h buffers with the sentinel bit pattern every launch
    // (graph-replay safe: per-iteration reset of the data-flags).
    hipMemsetAsync(h_f, 0xFF, (size_t)2 * 32 * 512 * 256 * sizeof(float), stream);
    k_wt4<<<512, 256, 0, stream>>>(W_hh_f, W_hh_b, Wt4);
    k_sgemm<<<dim3(16, 128), 256, 0, stream>>>(x, W_ih_f, W_ih_b, C);
    k_lstm5<<<512, 256, 0, stream>>>(C, Wt4, b_f, b_b, lengths, h_f, h_b);
    k_em<<<2048, 256, 65536, stream>>>(h_f, h_b, W_clf, b_clf, lengths, em);
    k_crfvit<<<64, 64, 0, stream>>>(em, targets, lengths, start_t, end_t, trans, numv, logZv, out);
    k_loss<<<1, 64, 0, stream>>>(numv, logZv, out);
}

// Round 9
// 2447.796 us; speedup vs baseline: 1.3302x; 1.3302x over previous
//
#include <hip/hip_runtime.h>
#include <hip/hip_bf16.h>

// Problem constants: B=32, T=512, D=768, H=256, K=32
// Outputs: d_out[0] = loss (f32), d_out[1 + b*512 + t] = preds as float.

#define NB 32
#define NT 512
#define ND 768
#define NH 256
#define NK 32

// ---------------------------------------------------------------------------
// K1: SGEMM  C[16384][2048] = x[16384][768] @ [W_ih_f | W_ih_b]^T
// 128x128 tile, 8x8 per thread, BK=16, fp32, double-buffered (verified R6).
// ---------------------------------------------------------------------------
__global__ __launch_bounds__(256) void k_sgemm(const float* __restrict__ A,
                                               const float* __restrict__ Wf,
                                               const float* __restrict__ Wb,
                                               float* __restrict__ C) {
    __shared__ float As[2][16][132];
    __shared__ float Bs[2][16][132];
    const int tid = threadIdx.x;
    const int bx = blockIdx.x;   // n tile: 0..15
    const int by = blockIdx.y;   // m tile: 0..127
    const int tx = tid & 15, ty = tid >> 4;
    const int sm = tid >> 2;           // 0..63
    const int sk = (tid & 3) * 4;      // 0,4,8,12
    float acc[8][8];
#pragma unroll
    for (int i = 0; i < 8; ++i)
#pragma unroll
        for (int j = 0; j < 8; ++j) acc[i][j] = 0.f;

    const float* Arow0 = A + (size_t)(by * 128 + sm) * ND + sk;
    const float* Arow1 = A + (size_t)(by * 128 + 64 + sm) * ND + sk;
    const int gn0 = bx * 128 + sm, gn1 = gn0 + 64;
    const float* W0 = (gn0 < 1024) ? (Wf + (size_t)gn0 * ND + sk) : (Wb + (size_t)(gn0 - 1024) * ND + sk);
    const float* W1 = (gn1 < 1024) ? (Wf + (size_t)gn1 * ND + sk) : (Wb + (size_t)(gn1 - 1024) * ND + sk);

    {
        float4 a0 = *(const float4*)(Arow0);
        float4 a1 = *(const float4*)(Arow1);
        float4 w0 = *(const float4*)(W0);
        float4 w1 = *(const float4*)(W1);
        As[0][sk + 0][sm] = a0.x; As[0][sk + 1][sm] = a0.y; As[0][sk + 2][sm] = a0.z; As[0][sk + 3][sm] = a0.w;
        As[0][sk + 0][64 + sm] = a1.x; As[0][sk + 1][64 + sm] = a1.y; As[0][sk + 2][64 + sm] = a1.z; As[0][sk + 3][64 + sm] = a1.w;
        Bs[0][sk + 0][sm] = w0.x; Bs[0][sk + 1][sm] = w0.y; Bs[0][sk + 2][sm] = w0.z; Bs[0][sk + 3][sm] = w0.w;
        Bs[0][sk + 0][64 + sm] = w1.x; Bs[0][sk + 1][64 + sm] = w1.y; Bs[0][sk + 2][64 + sm] = w1.z; Bs[0][sk + 3][64 + sm] = w1.w;
    }
    __syncthreads();

    int cur = 0;
    for (int k0 = 0; k0 < ND; k0 += 16) {
        const bool more = (k0 + 16) < ND;
        float4 na0, na1, nw0, nw1;
        if (more) {
            na0 = *(const float4*)(Arow0 + k0 + 16);
            na1 = *(const float4*)(Arow1 + k0 + 16);
            nw0 = *(const float4*)(W0 + k0 + 16);
            nw1 = *(const float4*)(W1 + k0 + 16);
        }
#pragma unroll
        for (int kk = 0; kk < 16; ++kk) {
            float a[8], b[8];
            *(float4*)&a[0] = *(const float4*)&As[cur][kk][ty * 4];
            *(float4*)&a[4] = *(const float4*)&As[cur][kk][64 + ty * 4];
            *(float4*)&b[0] = *(const float4*)&Bs[cur][kk][tx * 4];
            *(float4*)&b[4] = *(const float4*)&Bs[cur][kk][64 + tx * 4];
#pragma unroll
            for (int i = 0; i < 8; ++i)
#pragma unroll
                for (int j = 0; j < 8; ++j)
                    acc[i][j] = fmaf(a[i], b[j], acc[i][j]);
        }
        if (more) {
            const int nxt = cur ^ 1;
            As[nxt][sk + 0][sm] = na0.x; As[nxt][sk + 1][sm] = na0.y; As[nxt][sk + 2][sm] = na0.z; As[nxt][sk + 3][sm] = na0.w;
            As[nxt][sk + 0][64 + sm] = na1.x; As[nxt][sk + 1][64 + sm] = na1.y; As[nxt][sk + 2][64 + sm] = na1.z; As[nxt][sk + 3][64 + sm] = na1.w;
            Bs[nxt][sk + 0][sm] = nw0.x; Bs[nxt][sk + 1][sm] = nw0.y; Bs[nxt][sk + 2][sm] = nw0.z; Bs[nxt][sk + 3][sm] = nw0.w;
            Bs[nxt][sk + 0][64 + sm] = nw1.x; Bs[nxt][sk + 1][64 + sm] = nw1.y; Bs[nxt][sk + 2][64 + sm] = nw1.z; Bs[nxt][sk + 3][64 + sm] = nw1.w;
            __syncthreads();
            cur = nxt;
        }
    }
#pragma unroll
    for (int i = 0; i < 8; ++i) {
        int m = by * 128 + ((i < 4) ? (ty * 4 + i) : (64 + ty * 4 + (i - 4)));
        float* Crow = C + (size_t)m * 2048 + bx * 128;
        *(float4*)(Crow + tx * 4)      = make_float4(acc[i][0], acc[i][1], acc[i][2], acc[i][3]);
        *(float4*)(Crow + 64 + tx * 4) = make_float4(acc[i][4], acc[i][5], acc[i][6], acc[i][7]);
    }
}

// ---------------------------------------------------------------------------
// K1.5: transpose W_hh into Wt4[(dir*256 + k)*256 + j] =
//   {W[0*256+j][k], W[1*256+j][k], W[2*256+j][k], W[3*256+j][k]}
// ---------------------------------------------------------------------------
__global__ __launch_bounds__(256) void k_wt4(const float* __restrict__ Whf,
                                             const float* __restrict__ Whb,
                                             float4* __restrict__ Wt4) {
    int gid = blockIdx.x * 256 + threadIdx.x;
    if (gid >= 131072) return;
    int dir = gid >> 16;
    int k   = (gid >> 8) & 255;
    int j   = gid & 255;
    const float* W = dir ? Whb : Whf;
    Wt4[gid] = make_float4(W[(size_t)(0 * 256 + j) * 256 + k],
                           W[(size_t)(1 * 256 + j) * 256 + k],
                           W[(size_t)(2 * 256 + j) * 256 + k],
                           W[(size_t)(3 * 256 + j) * 256 + k]);
}

// ---------------------------------------------------------------------------
// K2: LSTM recurrence v5 — R6's verified wave-autonomous structure with W
// FULLY RESIDENT at 1 BLOCK/CU (the one untested config).
//
// Evidence: 1 block/CU configs (R2 2.06us/step, R6 2.29) beat 2 blocks/CU
// (R8 3.66 — SIMD sharing serializes FMA phases + doubles poll waves).
// R2/R6 declared 256 W floats/thread but VGPR_Count 148-152 => ~100+
// floats spilled to scratch, re-read each step (~150KB/block/step over L2
// ~= 1.1us/step — the gap to the latency floor).
//
// Fix, single delta from R6's k_lstm4: wreg[64] -> wreg[28] (112 VGPR,
// fits) + wlds[36][256] float4 in LDS (144KB). LDS total ~148KB => exactly
// 1 block/CU; grid 256 = all blocks co-resident (liveness by construction).
// wlds[u][tid] is written AND read only by thread tid: no barrier, and
// lane-consecutive 16B => conflict-free. Arithmetic order identical to R6.
// Everything else (poll, hsh distribute, butterfly, C/bias injection,
// sentinel protocol) is R6 verbatim.
// ---------------------------------------------------------------------------
__device__ __forceinline__ float sigm(float x) { return 1.f / (1.f + expf(-x)); }

__global__ __launch_bounds__(256, 1) void k_lstm6(const float* __restrict__ C,
                                                  const float4* __restrict__ Wt4,
                                                  const float* __restrict__ b_f,
                                                  const float* __restrict__ b_b,
                                                  const int* __restrict__ lengths,
                                                  float* __restrict__ h_f,
                                                  float* __restrict__ h_b) {
    __shared__ float4 wlds[36][256];   // 144 KB: W k-quads 28..63 per thread
    __shared__ float hsh[4][272];      // per-wave h(t-1); 64-f slices at stride 68
    const int tid = threadIdx.x;
    const int g = blockIdx.x & 63, s = blockIdx.x >> 6;
    const int b = g & 31, dir = g >> 5;
    const int j0 = s * 64;
    const float* bias = dir ? b_b : b_f;
    float* hdir = dir ? h_b : h_f;

    const int j = tid >> 2;        // 0..63
    const int kq = tid & 3;        // k-quad
    const int w = tid >> 6;        // wave id
    const int lane = tid & 63;

    float4 wreg[28];
    {
        const float4* wb = Wt4 + ((size_t)dir * 256 + kq * 64) * 256 + j0 + j;
#pragma unroll
        for (int u = 0; u < 28; ++u) wreg[u] = wb[(size_t)u * 256];
#pragma unroll
        for (int u = 0; u < 36; ++u) wlds[u][tid] = wb[(size_t)(28 + u) * 256];
    }
    float4 breg = make_float4(0.f, 0.f, 0.f, 0.f);
    if (kq == 0)
        breg = make_float4(bias[j0 + j], bias[256 + j0 + j],
                           bias[512 + j0 + j], bias[768 + j0 + j]);
    const int mylen = lengths[b];
    float creg = 0.f;
    __syncthreads();

    for (int t = 0; t < NT; ++t) {
        // C gate values for this thread's dim (plain loads; C is complete).
        // Issued before the poll so latency hides under it.
        float4 pre = make_float4(0.f, 0.f, 0.f, 0.f);
        if (kq == 0) {
            int src_t = t;
            if (dir) src_t = (t < mylen) ? (mylen - 1 - t) : t;
            const float* Crow = C + (size_t)(b * 512 + src_t) * 2048 + dir * 1024 + j0 + j;
            pre.x = Crow[0]; pre.y = Crow[256]; pre.z = Crow[512]; pre.w = Crow[768];
        }
        float4 acc = make_float4(0.f, 0.f, 0.f, 0.f);
        if (t > 0) {
            // wave-autonomous poll: lane owns dims [4*lane, 4*lane+4)
            const float* hp = hdir + ((size_t)b * 512 + (t - 1)) * 256 + 4 * lane;
            unsigned long long u0, u1;
            int guard = 0;
            for (;;) {
                u0 = __hip_atomic_load((const unsigned long long*)hp,
                                       __ATOMIC_RELAXED, __HIP_MEMORY_SCOPE_AGENT);
                u1 = __hip_atomic_load((const unsigned long long*)(hp + 2),
                                       __ATOMIC_RELAXED, __HIP_MEMORY_SCOPE_AGENT);
                if ((unsigned)(u0 & 0xFFFFFFFFu) != 0xFFFFFFFFu &&
                    (unsigned)(u0 >> 32)        != 0xFFFFFFFFu &&
                    (unsigned)(u1 & 0xFFFFFFFFu) != 0xFFFFFFFFu &&
                    (unsigned)(u1 >> 32)        != 0xFFFFFFFFu) break;
                if (++guard > (1 << 22)) break;   // liveness valve
            }
            // distribute within the wave via its private LDS row
            const int d0 = 4 * lane;
            float* dst = &hsh[w][(d0 >> 6) * 68 + (d0 & 63)];
            *(float4*)dst = make_float4(
                __uint_as_float((unsigned)(u0 & 0xFFFFFFFFu)),
                __uint_as_float((unsigned)(u0 >> 32)),
                __uint_as_float((unsigned)(u1 & 0xFFFFFFFFu)),
                __uint_as_float((unsigned)(u1 >> 32)));
            asm volatile("s_waitcnt lgkmcnt(0)" ::: "memory");
            __builtin_amdgcn_sched_barrier(0);
            // FMA over own kq slice (16-lane broadcast reads, conflict-free)
            const float* src = &hsh[w][kq * 68];
#pragma unroll
            for (int c = 0; c < 16; ++c) {
                float ha[4];
                *(float4*)ha = *(const float4*)(src + 4 * c);
#pragma unroll
                for (int i = 0; i < 4; ++i) {
                    float4 wv = (c < 7) ? wreg[c * 4 + i] : wlds[(c - 7) * 4 + i][tid];
                    acc.x = fmaf(wv.x, ha[i], acc.x);
                    acc.y = fmaf(wv.y, ha[i], acc.y);
                    acc.z = fmaf(wv.z, ha[i], acc.z);
                    acc.w = fmaf(wv.w, ha[i], acc.w);
                }
            }
        }
        if (kq == 0) {
            acc.x += pre.x + breg.x; acc.y += pre.y + breg.y;
            acc.z += pre.z + breg.z; acc.w += pre.w + breg.w;
        }
        // butterfly over kq (lane bits 0-1): all 4 lanes end bitwise-identical
#pragma unroll
        for (int off = 1; off <= 2; off <<= 1) {
            acc.x += __shfl_xor(acc.x, off);
            acc.y += __shfl_xor(acc.y, off);
            acc.z += __shfl_xor(acc.z, off);
            acc.w += __shfl_xor(acc.w, off);
        }
        float ig = sigm(acc.x), fg = sigm(acc.y), gt = tanhf(acc.z), og = sigm(acc.w);
        creg = fg * creg + ig * gt;
        float hn = og * tanhf(creg);
        if (kq == 0)
            __hip_atomic_store(hdir + ((size_t)b * 512 + t) * 256 + j0 + j, hn,
                               __ATOMIC_RELAXED, __HIP_MEMORY_SCOPE_AGENT);
        // write-once h slots: the store IS the publication.
    }
}

// ---------------------------------------------------------------------------
// K3: emissions  em[b][t][k] = hcat . W_clf[k] + b_clf[k]
// ---------------------------------------------------------------------------
__global__ __launch_bounds__(256) void k_em(const float* __restrict__ hf,
                                            const float* __restrict__ hb,
                                            const float* __restrict__ Wclf,
                                            const float* __restrict__ bclf,
                                            const int* __restrict__ lengths,
                                            float* __restrict__ em) {
    extern __shared__ float4 wc4[];   // [128][32]: wc4[jq*32+ko] = Wclf[ko][4jq..+3]
    const int tid = threadIdx.x;
    for (int idx = tid; idx < 4096; idx += 256) {
        int jq = idx >> 5, ko = idx & 31;
        wc4[idx] = *(const float4*)(Wclf + (size_t)ko * 512 + jq * 4);
    }
    __syncthreads();
    const int r = tid >> 5, ko = tid & 31;
    const int m = blockIdx.x * 8 + r;
    const int b = m >> 9, t = m & 511;
    const int len = lengths[b];
    const int rev = (t < len) ? (len - 1 - t) : t;
    const float* hfr = hf + (size_t)m * 256;
    const float* hbr = hb + (size_t)(b * 512 + rev) * 256;
    float acc = bclf[ko];
#pragma unroll 4
    for (int jq = 0; jq < 64; ++jq) {
        float4 h4 = *(const float4*)(hfr + jq * 4);
        float4 ww = wc4[jq * 32 + ko];
        acc += h4.x * ww.x + h4.y * ww.y + h4.z * ww.z + h4.w * ww.w;
    }
#pragma unroll 4
    for (int jq = 0; jq < 64; ++jq) {
        float4 h4 = *(const float4*)(hbr + jq * 4);
        float4 ww = wc4[(64 + jq) * 32 + ko];
        acc += h4.x * ww.x + h4.y * ww.y + h4.z * ww.z + h4.w * ww.w;
    }
    em[(size_t)m * 32 + ko] = acc;
}

// ---------------------------------------------------------------------------
// K4: CRF forward (logZ, num) and Viterbi (+backtrace).
// ---------------------------------------------------------------------------
__global__ __launch_bounds__(64) void k_crfvit(const float* __restrict__ em,
                                               const int* __restrict__ targets,
                                               const int* __restrict__ lengths,
                                               const float* __restrict__ start_t,
                                               const float* __restrict__ end_t,
                                               const float* __restrict__ trans,
                                               float* __restrict__ numv,
                                               float* __restrict__ logZv,
                                               float* __restrict__ out) {
    __shared__ float trans_s[32][33];
    __shared__ float vec[32];
    __shared__ unsigned char hist[511 * 32];
    const int tid = threadIdx.x;
    const int b = blockIdx.x & 31;
    const int mode = blockIdx.x >> 5;
    for (int idx = tid; idx < 1024; idx += 64) trans_s[idx >> 5][idx & 31] = trans[idx];
    const int len = lengths[b];
    const float* emb = em + (size_t)b * 512 * 32;
    const int k = tid & 31, half = tid >> 5;
    if (tid < 32) vec[tid] = start_t[tid] + emb[tid];
    __syncthreads();

    if (mode == 0) {
        for (int t = 1; t < NT; ++t) {
            bool mv = t < len;
            int kp0 = half * 16;
            float m = -1e30f;
#pragma unroll 4
            for (int i = 0; i < 16; ++i)
                m = fmaxf(m, vec[kp0 + i] + trans_s[kp0 + i][k]);
            float m2 = fmaxf(m, __shfl_xor(m, 32));
            float ssum = 0.f;
#pragma unroll 4
            for (int i = 0; i < 16; ++i)
                ssum += __expf(vec[kp0 + i] + trans_s[kp0 + i][k] - m2);
            ssum += __shfl_xor(ssum, 32);
            float anew = m2 + __logf(ssum) + emb[t * 32 + k];
            __syncthreads();
            if (half == 0 && mv) vec[k] = anew;
            __syncthreads();
        }
        float val = (tid < 32) ? vec[tid] + end_t[tid] : -1e30f;
        float m = val;
#pragma unroll
        for (int off = 32; off >= 1; off >>= 1) m = fmaxf(m, __shfl_xor(m, off));
        float e = (tid < 32) ? __expf(val - m) : 0.f;
#pragma unroll
        for (int off = 32; off >= 1; off >>= 1) e += __shfl_xor(e, off);
        if (tid == 0) logZv[b] = m + __logf(e);
        // numerator
        const int* tg = targets + b * 512;
        float partial = 0.f;
        for (int t = 1 + tid; t < NT; t += 64) {
            if (t < len) {
                int y0 = tg[t - 1], y1 = tg[t];
                partial += trans_s[y0][y1] + emb[t * 32 + y1];
            }
        }
#pragma unroll
        for (int off = 32; off >= 1; off >>= 1) partial += __shfl_xor(partial, off);
        if (tid == 0) {
            int y00 = tg[0];
            int yl = tg[len - 1];
            numv[b] = partial + start_t[y00] + emb[y00] + end_t[yl];
        }
    } else {
        for (int t = 1; t < NT; ++t) {
            bool mv = t < len;
            int kp0 = half * 16;
            float e = emb[t * 32 + k];
            float m = -1e30f; int mi = kp0;
#pragma unroll 4
            for (int i = 0; i < 16; ++i) {
                float v = (vec[kp0 + i] + trans_s[kp0 + i][k]) + e;
                if (v > m) { m = v; mi = kp0 + i; }
            }
            float mo = __shfl_xor(m, 32);
            int io = __shfl_xor(mi, 32);
            float mlow = half ? mo : m;   int ilow = half ? io : mi;
            float mhigh = half ? m : mo;  int ihigh = half ? mi : io;
            float bm; int bi;
            if (mhigh > mlow) { bm = mhigh; bi = ihigh; } else { bm = mlow; bi = ilow; }
            __syncthreads();
            if (half == 0) {
                hist[(t - 1) * 32 + k] = (unsigned char)(mv ? bi : k);
                if (mv) vec[k] = bm;
            }
            __syncthreads();
        }
        float val = (tid < 32) ? vec[tid] + end_t[tid] : -1e30f;
        int idx = (tid < 32) ? tid : 63;
#pragma unroll
        for (int off = 32; off >= 1; off >>= 1) {
            float vo = __shfl_xor(val, off);
            int io = __shfl_xor(idx, off);
            if (vo > val || (vo == val && io < idx)) { val = vo; idx = io; }
        }
        int cur = idx;
        float* ob = out + 1 + (size_t)b * 512;
        if (tid == 0) ob[511] = (511 < len) ? (float)cur : 0.f;
        for (int t2 = 510; t2 >= 0; --t2) {
            cur = hist[t2 * 32 + cur];
            if (tid == 0) ob[t2] = (t2 < len) ? (float)cur : 0.f;
        }
    }
}

// ---------------------------------------------------------------------------
// K5: loss = -mean(num - logZ)
// ---------------------------------------------------------------------------
__global__ __launch_bounds__(64) void k_loss(const float* __restrict__ numv,
                                             const float* __restrict__ logZv,
                                             float* __restrict__ out) {
    int tid = threadIdx.x;
    float v = (tid < 32) ? (logZv[tid] - numv[tid]) : 0.f;
#pragma unroll
    for (int off = 32; off >= 1; off >>= 1) v += __shfl_xor(v, off);
    if (tid == 0) out[0] = v / 32.f;
}

// ---------------------------------------------------------------------------
extern "C" void kernel_launch(void* const* d_in, const int* in_sizes, int n_in,
                              void* d_out, int out_size, void* d_ws, size_t ws_size,
                              hipStream_t stream) {
    const float* x       = (const float*)d_in[0];
    const int*   lengths = (const int*)d_in[1];
    // d_in[2] = mask (recomputed from lengths)
    const int*   targets = (const int*)d_in[3];
    const float* W_ih_f  = (const float*)d_in[4];
    const float* W_hh_f  = (const float*)d_in[5];
    const float* b_f     = (const float*)d_in[6];
    const float* W_ih_b  = (const float*)d_in[7];
    const float* W_hh_b  = (const float*)d_in[8];
    const float* b_b     = (const float*)d_in[9];
    const float* W_clf   = (const float*)d_in[10];
    const float* b_clf   = (const float*)d_in[11];
    const float* start_t = (const float*)d_in[12];
    const float* end_t   = (const float*)d_in[13];
    const float* trans   = (const float*)d_in[14];
    float* out = (float*)d_out;
    float* ws = (float*)d_ws;

    float* C     = ws;                                   // 16384*2048
    float* h_f   = C + (size_t)16384 * 2048;             // 32*512*256
    float* h_b   = h_f + (size_t)32 * 512 * 256;         // 32*512*256
    float* em    = h_b + (size_t)32 * 512 * 256;         // 32*512*32
    float4* Wt4  = (float4*)(em + (size_t)32 * 512 * 32);// 131072 float4
    float* numv  = (float*)(Wt4 + 131072);               // 32
    float* logZv = numv + 32;                            // 32

    // Re-poison h buffers with the sentinel bit pattern every launch
    // (graph-replay safe: per-iteration reset of the data-flags).
    hipMemsetAsync(h_f, 0xFF, (size_t)2 * 32 * 512 * 256 * sizeof(float), stream);
    k_wt4<<<512, 256, 0, stream>>>(W_hh_f, W_hh_b, Wt4);
    k_sgemm<<<dim3(16, 128), 256, 0, stream>>>(x, W_ih_f, W_ih_b, C);
    k_lstm6<<<256, 256, 0, stream>>>(C, Wt4, b_f, b_b, lengths, h_f, h_b);
    k_em<<<2048, 256, 65536, stream>>>(h_f, h_b, W_clf, b_clf, lengths, em);
    k_crfvit<<<64, 64, 0, stream>>>(em, targets, lengths, start_t, end_t, trans, numv, logZv, out);
    k_loss<<<1, 64, 0, stream>>>(numv, logZv, out);
}

// Round 10
// 2437.164 us; speedup vs baseline: 1.3360x; 1.0044x over previous
//
#include <hip/hip_runtime.h>
#include <hip/hip_bf16.h>

// Problem constants: B=32, T=512, D=768, H=256, K=32
// Outputs: d_out[0] = loss (f32), d_out[1 + b*512 + t] = preds as float.

#define NB 32
#define NT 512
#define ND 768
#define NH 256
#define NK 32

// ---------------------------------------------------------------------------
// K1: SGEMM  C[16384][2048] = x[16384][768] @ [W_ih_f | W_ih_b]^T
// 128x128 tile, 8x8 per thread, BK=16, fp32, double-buffered (verified R6).
// ---------------------------------------------------------------------------
__global__ __launch_bounds__(256) void k_sgemm(const float* __restrict__ A,
                                               const float* __restrict__ Wf,
                                               const float* __restrict__ Wb,
                                               float* __restrict__ C) {
    __shared__ float As[2][16][132];
    __shared__ float Bs[2][16][132];
    const int tid = threadIdx.x;
    const int bx = blockIdx.x;   // n tile: 0..15
    const int by = blockIdx.y;   // m tile: 0..127
    const int tx = tid & 15, ty = tid >> 4;
    const int sm = tid >> 2;           // 0..63
    const int sk = (tid & 3) * 4;      // 0,4,8,12
    float acc[8][8];
#pragma unroll
    for (int i = 0; i < 8; ++i)
#pragma unroll
        for (int j = 0; j < 8; ++j) acc[i][j] = 0.f;

    const float* Arow0 = A + (size_t)(by * 128 + sm) * ND + sk;
    const float* Arow1 = A + (size_t)(by * 128 + 64 + sm) * ND + sk;
    const int gn0 = bx * 128 + sm, gn1 = gn0 + 64;
    const float* W0 = (gn0 < 1024) ? (Wf + (size_t)gn0 * ND + sk) : (Wb + (size_t)(gn0 - 1024) * ND + sk);
    const float* W1 = (gn1 < 1024) ? (Wf + (size_t)gn1 * ND + sk) : (Wb + (size_t)(gn1 - 1024) * ND + sk);

    {
        float4 a0 = *(const float4*)(Arow0);
        float4 a1 = *(const float4*)(Arow1);
        float4 w0 = *(const float4*)(W0);
        float4 w1 = *(const float4*)(W1);
        As[0][sk + 0][sm] = a0.x; As[0][sk + 1][sm] = a0.y; As[0][sk + 2][sm] = a0.z; As[0][sk + 3][sm] = a0.w;
        As[0][sk + 0][64 + sm] = a1.x; As[0][sk + 1][64 + sm] = a1.y; As[0][sk + 2][64 + sm] = a1.z; As[0][sk + 3][64 + sm] = a1.w;
        Bs[0][sk + 0][sm] = w0.x; Bs[0][sk + 1][sm] = w0.y; Bs[0][sk + 2][sm] = w0.z; Bs[0][sk + 3][sm] = w0.w;
        Bs[0][sk + 0][64 + sm] = w1.x; Bs[0][sk + 1][64 + sm] = w1.y; Bs[0][sk + 2][64 + sm] = w1.z; Bs[0][sk + 3][64 + sm] = w1.w;
    }
    __syncthreads();

    int cur = 0;
    for (int k0 = 0; k0 < ND; k0 += 16) {
        const bool more = (k0 + 16) < ND;
        float4 na0, na1, nw0, nw1;
        if (more) {
            na0 = *(const float4*)(Arow0 + k0 + 16);
            na1 = *(const float4*)(Arow1 + k0 + 16);
            nw0 = *(const float4*)(W0 + k0 + 16);
            nw1 = *(const float4*)(W1 + k0 + 16);
        }
#pragma unroll
        for (int kk = 0; kk < 16; ++kk) {
            float a[8], b[8];
            *(float4*)&a[0] = *(const float4*)&As[cur][kk][ty * 4];
            *(float4*)&a[4] = *(const float4*)&As[cur][kk][64 + ty * 4];
            *(float4*)&b[0] = *(const float4*)&Bs[cur][kk][tx * 4];
            *(float4*)&b[4] = *(const float4*)&Bs[cur][kk][64 + tx * 4];
#pragma unroll
            for (int i = 0; i < 8; ++i)
#pragma unroll
                for (int j = 0; j < 8; ++j)
                    acc[i][j] = fmaf(a[i], b[j], acc[i][j]);
        }
        if (more) {
            const int nxt = cur ^ 1;
            As[nxt][sk + 0][sm] = na0.x; As[nxt][sk + 1][sm] = na0.y; As[nxt][sk + 2][sm] = na0.z; As[nxt][sk + 3][sm] = na0.w;
            As[nxt][sk + 0][64 + sm] = na1.x; As[nxt][sk + 1][64 + sm] = na1.y; As[nxt][sk + 2][64 + sm] = na1.z; As[nxt][sk + 3][64 + sm] = na1.w;
            Bs[nxt][sk + 0][sm] = nw0.x; Bs[nxt][sk + 1][sm] = nw0.y; Bs[nxt][sk + 2][sm] = nw0.z; Bs[nxt][sk + 3][sm] = nw0.w;
            Bs[nxt][sk + 0][64 + sm] = nw1.x; Bs[nxt][sk + 1][64 + sm] = nw1.y; Bs[nxt][sk + 2][64 + sm] = nw1.z; Bs[nxt][sk + 3][64 + sm] = nw1.w;
            __syncthreads();
            cur = nxt;
        }
    }
#pragma unroll
    for (int i = 0; i < 8; ++i) {
        int m = by * 128 + ((i < 4) ? (ty * 4 + i) : (64 + ty * 4 + (i - 4)));
        float* Crow = C + (size_t)m * 2048 + bx * 128;
        *(float4*)(Crow + tx * 4)      = make_float4(acc[i][0], acc[i][1], acc[i][2], acc[i][3]);
        *(float4*)(Crow + 64 + tx * 4) = make_float4(acc[i][4], acc[i][5], acc[i][6], acc[i][7]);
    }
}

// ---------------------------------------------------------------------------
// K1.5: transpose W_hh into Wt4[(dir*256 + k)*256 + j] =
//   {W[0*256+j][k], W[1*256+j][k], W[2*256+j][k], W[3*256+j][k]}
// ---------------------------------------------------------------------------
__global__ __launch_bounds__(256) void k_wt4(const float* __restrict__ Whf,
                                             const float* __restrict__ Whb,
                                             float4* __restrict__ Wt4) {
    int gid = blockIdx.x * 256 + threadIdx.x;
    if (gid >= 131072) return;
    int dir = gid >> 16;
    int k   = (gid >> 8) & 255;
    int j   = gid & 255;
    const float* W = dir ? Whb : Whf;
    Wt4[gid] = make_float4(W[(size_t)(0 * 256 + j) * 256 + k],
                           W[(size_t)(1 * 256 + j) * 256 + k],
                           W[(size_t)(2 * 256 + j) * 256 + k],
                           W[(size_t)(3 * 256 + j) * 256 + k]);
}

// ---------------------------------------------------------------------------
// K2: LSTM recurrence (R9-verified, 1055us — at the agent-atomic exchange
// floor; left untouched). W fully resident: wreg[28] VGPR + wlds[36][256]
// LDS (144KB) => 1 block/CU, grid 256 all-co-resident, liveness by
// construction. Wave-autonomous poll/distribute/FMA/butterfly.
// ---------------------------------------------------------------------------
__device__ __forceinline__ float sigm(float x) { return 1.f / (1.f + expf(-x)); }

__global__ __launch_bounds__(256, 1) void k_lstm6(const float* __restrict__ C,
                                                  const float4* __restrict__ Wt4,
                                                  const float* __restrict__ b_f,
                                                  const float* __restrict__ b_b,
                                                  const int* __restrict__ lengths,
                                                  float* __restrict__ h_f,
                                                  float* __restrict__ h_b) {
    __shared__ float4 wlds[36][256];   // 144 KB: W k-quads 28..63 per thread
    __shared__ float hsh[4][272];      // per-wave h(t-1); 64-f slices at stride 68
    const int tid = threadIdx.x;
    const int g = blockIdx.x & 63, s = blockIdx.x >> 6;
    const int b = g & 31, dir = g >> 5;
    const int j0 = s * 64;
    const float* bias = dir ? b_b : b_f;
    float* hdir = dir ? h_b : h_f;

    const int j = tid >> 2;        // 0..63
    const int kq = tid & 3;        // k-quad
    const int w = tid >> 6;        // wave id
    const int lane = tid & 63;

    float4 wreg[28];
    {
        const float4* wb = Wt4 + ((size_t)dir * 256 + kq * 64) * 256 + j0 + j;
#pragma unroll
        for (int u = 0; u < 28; ++u) wreg[u] = wb[(size_t)u * 256];
#pragma unroll
        for (int u = 0; u < 36; ++u) wlds[u][tid] = wb[(size_t)(28 + u) * 256];
    }
    float4 breg = make_float4(0.f, 0.f, 0.f, 0.f);
    if (kq == 0)
        breg = make_float4(bias[j0 + j], bias[256 + j0 + j],
                           bias[512 + j0 + j], bias[768 + j0 + j]);
    const int mylen = lengths[b];
    float creg = 0.f;
    __syncthreads();

    for (int t = 0; t < NT; ++t) {
        float4 pre = make_float4(0.f, 0.f, 0.f, 0.f);
        if (kq == 0) {
            int src_t = t;
            if (dir) src_t = (t < mylen) ? (mylen - 1 - t) : t;
            const float* Crow = C + (size_t)(b * 512 + src_t) * 2048 + dir * 1024 + j0 + j;
            pre.x = Crow[0]; pre.y = Crow[256]; pre.z = Crow[512]; pre.w = Crow[768];
        }
        float4 acc = make_float4(0.f, 0.f, 0.f, 0.f);
        if (t > 0) {
            const float* hp = hdir + ((size_t)b * 512 + (t - 1)) * 256 + 4 * lane;
            unsigned long long u0, u1;
            int guard = 0;
            for (;;) {
                u0 = __hip_atomic_load((const unsigned long long*)hp,
                                       __ATOMIC_RELAXED, __HIP_MEMORY_SCOPE_AGENT);
                u1 = __hip_atomic_load((const unsigned long long*)(hp + 2),
                                       __ATOMIC_RELAXED, __HIP_MEMORY_SCOPE_AGENT);
                if ((unsigned)(u0 & 0xFFFFFFFFu) != 0xFFFFFFFFu &&
                    (unsigned)(u0 >> 32)        != 0xFFFFFFFFu &&
                    (unsigned)(u1 & 0xFFFFFFFFu) != 0xFFFFFFFFu &&
                    (unsigned)(u1 >> 32)        != 0xFFFFFFFFu) break;
                if (++guard > (1 << 22)) break;   // liveness valve
            }
            const int d0 = 4 * lane;
            float* dst = &hsh[w][(d0 >> 6) * 68 + (d0 & 63)];
            *(float4*)dst = make_float4(
                __uint_as_float((unsigned)(u0 & 0xFFFFFFFFu)),
                __uint_as_float((unsigned)(u0 >> 32)),
                __uint_as_float((unsigned)(u1 & 0xFFFFFFFFu)),
                __uint_as_float((unsigned)(u1 >> 32)));
            asm volatile("s_waitcnt lgkmcnt(0)" ::: "memory");
            __builtin_amdgcn_sched_barrier(0);
            const float* src = &hsh[w][kq * 68];
#pragma unroll
            for (int c = 0; c < 16; ++c) {
                float ha[4];
                *(float4*)ha = *(const float4*)(src + 4 * c);
#pragma unroll
                for (int i = 0; i < 4; ++i) {
                    float4 wv = (c < 7) ? wreg[c * 4 + i] : wlds[(c - 7) * 4 + i][tid];
                    acc.x = fmaf(wv.x, ha[i], acc.x);
                    acc.y = fmaf(wv.y, ha[i], acc.y);
                    acc.z = fmaf(wv.z, ha[i], acc.z);
                    acc.w = fmaf(wv.w, ha[i], acc.w);
                }
            }
        }
        if (kq == 0) {
            acc.x += pre.x + breg.x; acc.y += pre.y + breg.y;
            acc.z += pre.z + breg.z; acc.w += pre.w + breg.w;
        }
#pragma unroll
        for (int off = 1; off <= 2; off <<= 1) {
            acc.x += __shfl_xor(acc.x, off);
            acc.y += __shfl_xor(acc.y, off);
            acc.z += __shfl_xor(acc.z, off);
            acc.w += __shfl_xor(acc.w, off);
        }
        float ig = sigm(acc.x), fg = sigm(acc.y), gt = tanhf(acc.z), og = sigm(acc.w);
        creg = fg * creg + ig * gt;
        float hn = og * tanhf(creg);
        if (kq == 0)
            __hip_atomic_store(hdir + ((size_t)b * 512 + t) * 256 + j0 + j, hn,
                               __ATOMIC_RELAXED, __HIP_MEMORY_SCOPE_AGENT);
    }
}

// ---------------------------------------------------------------------------
// K3: emissions  em[b][t][k] = hcat . W_clf[k] + b_clf[k]
// ---------------------------------------------------------------------------
__global__ __launch_bounds__(256) void k_em(const float* __restrict__ hf,
                                            const float* __restrict__ hb,
                                            const float* __restrict__ Wclf,
                                            const float* __restrict__ bclf,
                                            const int* __restrict__ lengths,
                                            float* __restrict__ em) {
    extern __shared__ float4 wc4[];   // [128][32]: wc4[jq*32+ko] = Wclf[ko][4jq..+3]
    const int tid = threadIdx.x;
    for (int idx = tid; idx < 4096; idx += 256) {
        int jq = idx >> 5, ko = idx & 31;
        wc4[idx] = *(const float4*)(Wclf + (size_t)ko * 512 + jq * 4);
    }
    __syncthreads();
    const int r = tid >> 5, ko = tid & 31;
    const int m = blockIdx.x * 8 + r;
    const int b = m >> 9, t = m & 511;
    const int len = lengths[b];
    const int rev = (t < len) ? (len - 1 - t) : t;
    const float* hfr = hf + (size_t)m * 256;
    const float* hbr = hb + (size_t)(b * 512 + rev) * 256;
    float acc = bclf[ko];
#pragma unroll 4
    for (int jq = 0; jq < 64; ++jq) {
        float4 h4 = *(const float4*)(hfr + jq * 4);
        float4 ww = wc4[jq * 32 + ko];
        acc += h4.x * ww.x + h4.y * ww.y + h4.z * ww.z + h4.w * ww.w;
    }
#pragma unroll 4
    for (int jq = 0; jq < 64; ++jq) {
        float4 h4 = *(const float4*)(hbr + jq * 4);
        float4 ww = wc4[(64 + jq) * 32 + ko];
        acc += h4.x * ww.x + h4.y * ww.y + h4.z * ww.z + h4.w * ww.w;
    }
    em[(size_t)m * 32 + ko] = acc;
}

// ---------------------------------------------------------------------------
// K4: CRF forward (logZ, num) and Viterbi (+backtrace) — WAVE-SYNC version.
// Block = 64 threads = EXACTLY ONE wave64. DS operations from a single wave
// execute in FIFO program order, so the per-step vec[]/hist[] write->read
// ordering needs NO __syncthreads (2 barriers/step removed from the 511-step
// serial chain). emb row t+1 is prefetched while step t computes, taking the
// dependent global load off the critical path. Arithmetic order identical.
// ---------------------------------------------------------------------------
__global__ __launch_bounds__(64) void k_crfvit(const float* __restrict__ em,
                                               const int* __restrict__ targets,
                                               const int* __restrict__ lengths,
                                               const float* __restrict__ start_t,
                                               const float* __restrict__ end_t,
                                               const float* __restrict__ trans,
                                               float* __restrict__ numv,
                                               float* __restrict__ logZv,
                                               float* __restrict__ out) {
    __shared__ float trans_s[32][33];
    __shared__ float vec[32];
    __shared__ unsigned char hist[511 * 32];
    const int tid = threadIdx.x;
    const int b = blockIdx.x & 31;
    const int mode = blockIdx.x >> 5;
    for (int idx = tid; idx < 1024; idx += 64) trans_s[idx >> 5][idx & 31] = trans[idx];
    const int len = lengths[b];
    const float* emb = em + (size_t)b * 512 * 32;
    const int k = tid & 31, half = tid >> 5;
    if (tid < 32) vec[tid] = start_t[tid] + emb[tid];
    // no barrier: single wave, DS FIFO order covers trans_s/vec init->use

    if (mode == 0) {
        float e_cur = emb[32 + k];            // row t=1, broadcast to both halves
        for (int t = 1; t < NT; ++t) {
            float e_next = (t + 1 < NT) ? emb[(t + 1) * 32 + k] : 0.f;
            bool mv = t < len;
            int kp0 = half * 16;
            float m = -1e30f;
#pragma unroll 4
            for (int i = 0; i < 16; ++i)
                m = fmaxf(m, vec[kp0 + i] + trans_s[kp0 + i][k]);
            float m2 = fmaxf(m, __shfl_xor(m, 32));
            float ssum = 0.f;
#pragma unroll 4
            for (int i = 0; i < 16; ++i)
                ssum += __expf(vec[kp0 + i] + trans_s[kp0 + i][k] - m2);
            ssum += __shfl_xor(ssum, 32);
            float anew = m2 + __logf(ssum) + e_cur;
            if (half == 0 && mv) vec[k] = anew;   // same-wave DS order: safe
            e_cur = e_next;
        }
        float val = (tid < 32) ? vec[tid] + end_t[tid] : -1e30f;
        float m = val;
#pragma unroll
        for (int off = 32; off >= 1; off >>= 1) m = fmaxf(m, __shfl_xor(m, off));
        float e = (tid < 32) ? __expf(val - m) : 0.f;
#pragma unroll
        for (int off = 32; off >= 1; off >>= 1) e += __shfl_xor(e, off);
        if (tid == 0) logZv[b] = m + __logf(e);
        // numerator
        const int* tg = targets + b * 512;
        float partial = 0.f;
        for (int t = 1 + tid; t < NT; t += 64) {
            if (t < len) {
                int y0 = tg[t - 1], y1 = tg[t];
                partial += trans_s[y0][y1] + emb[t * 32 + y1];
            }
        }
#pragma unroll
        for (int off = 32; off >= 1; off >>= 1) partial += __shfl_xor(partial, off);
        if (tid == 0) {
            int y00 = tg[0];
            int yl = tg[len - 1];
            numv[b] = partial + start_t[y00] + emb[y00] + end_t[yl];
        }
    } else {
        float e_cur = emb[32 + k];
        for (int t = 1; t < NT; ++t) {
            float e_next = (t + 1 < NT) ? emb[(t + 1) * 32 + k] : 0.f;
            bool mv = t < len;
            int kp0 = half * 16;
            float e = e_cur;
            float m = -1e30f; int mi = kp0;
#pragma unroll 4
            for (int i = 0; i < 16; ++i) {
                float v = (vec[kp0 + i] + trans_s[kp0 + i][k]) + e;
                if (v > m) { m = v; mi = kp0 + i; }
            }
            float mo = __shfl_xor(m, 32);
            int io = __shfl_xor(mi, 32);
            float mlow = half ? mo : m;   int ilow = half ? io : mi;
            float mhigh = half ? m : mo;  int ihigh = half ? mi : io;
            float bm; int bi;
            if (mhigh > mlow) { bm = mhigh; bi = ihigh; } else { bm = mlow; bi = ilow; }
            if (half == 0) {
                hist[(t - 1) * 32 + k] = (unsigned char)(mv ? bi : k);
                if (mv) vec[k] = bm;              // same-wave DS order: safe
            }
            e_cur = e_next;
        }
        float val = (tid < 32) ? vec[tid] + end_t[tid] : -1e30f;
        int idx = (tid < 32) ? tid : 63;
#pragma unroll
        for (int off = 32; off >= 1; off >>= 1) {
            float vo = __shfl_xor(val, off);
            int io = __shfl_xor(idx, off);
            if (vo > val || (vo == val && io < idx)) { val = vo; idx = io; }
        }
        int cur = idx;
        float* ob = out + 1 + (size_t)b * 512;
        if (tid == 0) ob[511] = (511 < len) ? (float)cur : 0.f;
        for (int t2 = 510; t2 >= 0; --t2) {
            cur = hist[t2 * 32 + cur];
            if (tid == 0) ob[t2] = (t2 < len) ? (float)cur : 0.f;
        }
    }
}

// ---------------------------------------------------------------------------
// K5: loss = -mean(num - logZ)
// ---------------------------------------------------------------------------
__global__ __launch_bounds__(64) void k_loss(const float* __restrict__ numv,
                                             const float* __restrict__ logZv,
                                             float* __restrict__ out) {
    int tid = threadIdx.x;
    float v = (tid < 32) ? (logZv[tid] - numv[tid]) : 0.f;
#pragma unroll
    for (int off = 32; off >= 1; off >>= 1) v += __shfl_xor(v, off);
    if (tid == 0) out[0] = v / 32.f;
}

// ---------------------------------------------------------------------------
extern "C" void kernel_launch(void* const* d_in, const int* in_sizes, int n_in,
                              void* d_out, int out_size, void* d_ws, size_t ws_size,
                              hipStream_t stream) {
    const float* x       = (const float*)d_in[0];
    const int*   lengths = (const int*)d_in[1];
    // d_in[2] = mask (recomputed from lengths)
    const int*   targets = (const int*)d_in[3];
    const float* W_ih_f  = (const float*)d_in[4];
    const float* W_hh_f  = (const float*)d_in[5];
    const float* b_f     = (const float*)d_in[6];
    const float* W_ih_b  = (const float*)d_in[7];
    const float* W_hh_b  = (const float*)d_in[8];
    const float* b_b     = (const float*)d_in[9];
    const float* W_clf   = (const float*)d_in[10];
    const float* b_clf   = (const float*)d_in[11];
    const float* start_t = (const float*)d_in[12];
    const float* end_t   = (const float*)d_in[13];
    const float* trans   = (const float*)d_in[14];
    float* out = (float*)d_out;
    float* ws = (float*)d_ws;

    float* C     = ws;                                   // 16384*2048
    float* h_f   = C + (size_t)16384 * 2048;             // 32*512*256
    float* h_b   = h_f + (size_t)32 * 512 * 256;         // 32*512*256
    float* em    = h_b + (size_t)32 * 512 * 256;         // 32*512*32
    float4* Wt4  = (float4*)(em + (size_t)32 * 512 * 32);// 131072 float4
    float* numv  = (float*)(Wt4 + 131072);               // 32
    float* logZv = numv + 32;                            // 32

    // Re-poison h buffers with the sentinel bit pattern every launch
    // (graph-replay safe: per-iteration reset of the data-flags).
    hipMemsetAsync(h_f, 0xFF, (size_t)2 * 32 * 512 * 256 * sizeof(float), stream);
    k_wt4<<<512, 256, 0, stream>>>(W_hh_f, W_hh_b, Wt4);
    k_sgemm<<<dim3(16, 128), 256, 0, stream>>>(x, W_ih_f, W_ih_b, C);
    k_lstm6<<<256, 256, 0, stream>>>(C, Wt4, b_f, b_b, lengths, h_f, h_b);
    k_em<<<2048, 256, 65536, stream>>>(h_f, h_b, W_clf, b_clf, lengths, em);
    k_crfvit<<<64, 64, 0, stream>>>(em, targets, lengths, start_t, end_t, trans, numv, logZv, out);
    k_loss<<<1, 64, 0, stream>>>(numv, logZv, out);
}

// Round 11
// 2080.543 us; speedup vs baseline: 1.5651x; 1.1714x over previous
//
#include <hip/hip_runtime.h>
#include <hip/hip_bf16.h>

// Problem constants: B=32, T=512, D=768, H=256, K=32
// Outputs: d_out[0] = loss (f32), d_out[1 + b*512 + t] = preds as float.

#define NB 32
#define NT 512
#define ND 768
#define NH 256
#define NK 32

using bf16x8 = __attribute__((ext_vector_type(8))) short;   // 8 bf16 (4 VGPRs)
using f32x4  = __attribute__((ext_vector_type(4))) float;   // 4 fp32

__device__ __forceinline__ ushort f2bf_rne(float f) {
    unsigned u = __float_as_uint(f);
    return (ushort)((u + 0x7FFFu + ((u >> 16) & 1u)) >> 16);
}
__device__ __forceinline__ float bf2f(ushort h) {
    return __uint_as_float(((unsigned)h) << 16);
}

// ---------------------------------------------------------------------------
// K1: SGEMM  C[16384][2048] = x[16384][768] @ [W_ih_f | W_ih_b]^T
// MFMA bf16 split-precision: x = xh + xl, W = wh + wl (hi/lo bf16, RNE);
// acc += xh*wh + xh*wl + xl*wh + xl*wl  (all in one fp32 MFMA accumulator)
// -> residual ~2^-18/product, dot error ~1e-6: fp32-equivalent.
// Tile 128x128, BK=32, 4 waves; v_mfma_f32_16x16x32_bf16.
// Fragment layouts (guide-verified): A/B: lane&15 = row/col,
// k = (lane>>4)*8 + elem;  C/D: col = lane&15, row = (lane>>4)*4 + reg.
// LDS rows padded to 40 shorts (80B): 16B-aligned b128, even quad spread.
// ---------------------------------------------------------------------------
__global__ __launch_bounds__(256) void k_sgemm(const float* __restrict__ A,
                                               const float* __restrict__ Wf,
                                               const float* __restrict__ Wb,
                                               float* __restrict__ C) {
    __shared__ ushort Ah[128][40], Al[128][40], Bh[128][40], Bl[128][40];
    const int tid = threadIdx.x;
    const int bx = blockIdx.x;   // n tile: 0..15
    const int by = blockIdx.y;   // m tile: 0..127
    const int w = tid >> 6, lane = tid & 63;
    const int l15 = lane & 15, koff = (lane >> 4) * 8;

    // staging mapping: thread -> (row 0..127, k-half 0/1)
    const int srow = tid >> 1, shalf = tid & 1;
    const float* Asrc = A + (size_t)(by * 128 + srow) * ND + shalf * 16;
    const int gn = bx * 128 + srow;
    const float* Bsrc = ((gn < 1024) ? (Wf + (size_t)gn * ND)
                                     : (Wb + (size_t)(gn - 1024) * ND)) + shalf * 16;

    f32x4 acc0[8], acc1[8];
#pragma unroll
    for (int ns = 0; ns < 8; ++ns) {
        acc0[ns] = (f32x4){0.f, 0.f, 0.f, 0.f};
        acc1[ns] = (f32x4){0.f, 0.f, 0.f, 0.f};
    }

    for (int k0 = 0; k0 < ND; k0 += 32) {
        // global loads issued before the barrier (overlap prior compute)
        float fa[16], fb[16];
        *(float4*)&fa[0]  = *(const float4*)(Asrc + k0 + 0);
        *(float4*)&fa[4]  = *(const float4*)(Asrc + k0 + 4);
        *(float4*)&fa[8]  = *(const float4*)(Asrc + k0 + 8);
        *(float4*)&fa[12] = *(const float4*)(Asrc + k0 + 12);
        *(float4*)&fb[0]  = *(const float4*)(Bsrc + k0 + 0);
        *(float4*)&fb[4]  = *(const float4*)(Bsrc + k0 + 4);
        *(float4*)&fb[8]  = *(const float4*)(Bsrc + k0 + 8);
        *(float4*)&fb[12] = *(const float4*)(Bsrc + k0 + 12);
        __syncthreads();   // WAR: prior iteration's frag reads complete
        bf16x8 AH0, AH1, AL0, AL1, BH0, BH1, BL0, BL1;
#pragma unroll
        for (int i = 0; i < 8; ++i) {
            ushort h;
            h = f2bf_rne(fa[i]);     AH0[i] = (short)h; AL0[i] = (short)f2bf_rne(fa[i]     - bf2f(h));
            h = f2bf_rne(fa[8 + i]); AH1[i] = (short)h; AL1[i] = (short)f2bf_rne(fa[8 + i] - bf2f(h));
            h = f2bf_rne(fb[i]);     BH0[i] = (short)h; BL0[i] = (short)f2bf_rne(fb[i]     - bf2f(h));
            h = f2bf_rne(fb[8 + i]); BH1[i] = (short)h; BL1[i] = (short)f2bf_rne(fb[8 + i] - bf2f(h));
        }
        {
            const int c = shalf * 16;
            *(bf16x8*)&Ah[srow][c] = AH0; *(bf16x8*)&Ah[srow][c + 8] = AH1;
            *(bf16x8*)&Al[srow][c] = AL0; *(bf16x8*)&Al[srow][c + 8] = AL1;
            *(bf16x8*)&Bh[srow][c] = BH0; *(bf16x8*)&Bh[srow][c + 8] = BH1;
            *(bf16x8*)&Bl[srow][c] = BL0; *(bf16x8*)&Bl[srow][c + 8] = BL1;
        }
        __syncthreads();   // RAW: tiles staged

        // A fragments for this wave's two 16-row strips (hi & lo planes)
        bf16x8 a0h = *(const bf16x8*)&Ah[w * 32 + l15][koff];
        bf16x8 a0l = *(const bf16x8*)&Al[w * 32 + l15][koff];
        bf16x8 a1h = *(const bf16x8*)&Ah[w * 32 + 16 + l15][koff];
        bf16x8 a1l = *(const bf16x8*)&Al[w * 32 + 16 + l15][koff];
#pragma unroll
        for (int ns = 0; ns < 8; ++ns) {
            bf16x8 bh = *(const bf16x8*)&Bh[ns * 16 + l15][koff];
            bf16x8 bl = *(const bf16x8*)&Bl[ns * 16 + l15][koff];
            acc0[ns] = __builtin_amdgcn_mfma_f32_16x16x32_bf16(a0h, bh, acc0[ns], 0, 0, 0);
            acc0[ns] = __builtin_amdgcn_mfma_f32_16x16x32_bf16(a0h, bl, acc0[ns], 0, 0, 0);
            acc0[ns] = __builtin_amdgcn_mfma_f32_16x16x32_bf16(a0l, bh, acc0[ns], 0, 0, 0);
            acc0[ns] = __builtin_amdgcn_mfma_f32_16x16x32_bf16(a0l, bl, acc0[ns], 0, 0, 0);
            acc1[ns] = __builtin_amdgcn_mfma_f32_16x16x32_bf16(a1h, bh, acc1[ns], 0, 0, 0);
            acc1[ns] = __builtin_amdgcn_mfma_f32_16x16x32_bf16(a1h, bl, acc1[ns], 0, 0, 0);
            acc1[ns] = __builtin_amdgcn_mfma_f32_16x16x32_bf16(a1l, bh, acc1[ns], 0, 0, 0);
            acc1[ns] = __builtin_amdgcn_mfma_f32_16x16x32_bf16(a1l, bl, acc1[ns], 0, 0, 0);
        }
    }
    // epilogue: C/D layout col=lane&15, row=(lane>>4)*4+reg
    const int kg4 = (lane >> 4) * 4;
#pragma unroll
    for (int ns = 0; ns < 8; ++ns) {
        const int gcol = bx * 128 + ns * 16 + l15;
#pragma unroll
        for (int r = 0; r < 4; ++r) {
            int gm0 = by * 128 + w * 32 + kg4 + r;
            C[(size_t)gm0 * 2048 + gcol] = acc0[ns][r];
            int gm1 = gm0 + 16;
            C[(size_t)gm1 * 2048 + gcol] = acc1[ns][r];
        }
    }
}

// ---------------------------------------------------------------------------
// K1.5: transpose W_hh into Wt4[(dir*256 + k)*256 + j] =
//   {W[0*256+j][k], W[1*256+j][k], W[2*256+j][k], W[3*256+j][k]}
// ---------------------------------------------------------------------------
__global__ __launch_bounds__(256) void k_wt4(const float* __restrict__ Whf,
                                             const float* __restrict__ Whb,
                                             float4* __restrict__ Wt4) {
    int gid = blockIdx.x * 256 + threadIdx.x;
    if (gid >= 131072) return;
    int dir = gid >> 16;
    int k   = (gid >> 8) & 255;
    int j   = gid & 255;
    const float* W = dir ? Whb : Whf;
    Wt4[gid] = make_float4(W[(size_t)(0 * 256 + j) * 256 + k],
                           W[(size_t)(1 * 256 + j) * 256 + k],
                           W[(size_t)(2 * 256 + j) * 256 + k],
                           W[(size_t)(3 * 256 + j) * 256 + k]);
}

// ---------------------------------------------------------------------------
// K2: LSTM recurrence (R9-verified, 1055us — at the agent-atomic exchange
// floor; left untouched). W fully resident: wreg[28] VGPR + wlds[36][256]
// LDS (144KB) => 1 block/CU, grid 256 all-co-resident, liveness by
// construction. Wave-autonomous poll/distribute/FMA/butterfly.
// ---------------------------------------------------------------------------
__device__ __forceinline__ float sigm(float x) { return 1.f / (1.f + expf(-x)); }

__global__ __launch_bounds__(256, 1) void k_lstm6(const float* __restrict__ C,
                                                  const float4* __restrict__ Wt4,
                                                  const float* __restrict__ b_f,
                                                  const float* __restrict__ b_b,
                                                  const int* __restrict__ lengths,
                                                  float* __restrict__ h_f,
                                                  float* __restrict__ h_b) {
    __shared__ float4 wlds[36][256];   // 144 KB: W k-quads 28..63 per thread
    __shared__ float hsh[4][272];      // per-wave h(t-1); 64-f slices at stride 68
    const int tid = threadIdx.x;
    const int g = blockIdx.x & 63, s = blockIdx.x >> 6;
    const int b = g & 31, dir = g >> 5;
    const int j0 = s * 64;
    const float* bias = dir ? b_b : b_f;
    float* hdir = dir ? h_b : h_f;

    const int j = tid >> 2;        // 0..63
    const int kq = tid & 3;        // k-quad
    const int w = tid >> 6;        // wave id
    const int lane = tid & 63;

    float4 wreg[28];
    {
        const float4* wb = Wt4 + ((size_t)dir * 256 + kq * 64) * 256 + j0 + j;
#pragma unroll
        for (int u = 0; u < 28; ++u) wreg[u] = wb[(size_t)u * 256];
#pragma unroll
        for (int u = 0; u < 36; ++u) wlds[u][tid] = wb[(size_t)(28 + u) * 256];
    }
    float4 breg = make_float4(0.f, 0.f, 0.f, 0.f);
    if (kq == 0)
        breg = make_float4(bias[j0 + j], bias[256 + j0 + j],
                           bias[512 + j0 + j], bias[768 + j0 + j]);
    const int mylen = lengths[b];
    float creg = 0.f;
    __syncthreads();

    for (int t = 0; t < NT; ++t) {
        float4 pre = make_float4(0.f, 0.f, 0.f, 0.f);
        if (kq == 0) {
            int src_t = t;
            if (dir) src_t = (t < mylen) ? (mylen - 1 - t) : t;
            const float* Crow = C + (size_t)(b * 512 + src_t) * 2048 + dir * 1024 + j0 + j;
            pre.x = Crow[0]; pre.y = Crow[256]; pre.z = Crow[512]; pre.w = Crow[768];
        }
        float4 acc = make_float4(0.f, 0.f, 0.f, 0.f);
        if (t > 0) {
            const float* hp = hdir + ((size_t)b * 512 + (t - 1)) * 256 + 4 * lane;
            unsigned long long u0, u1;
            int guard = 0;
            for (;;) {
                u0 = __hip_atomic_load((const unsigned long long*)hp,
                                       __ATOMIC_RELAXED, __HIP_MEMORY_SCOPE_AGENT);
                u1 = __hip_atomic_load((const unsigned long long*)(hp + 2),
                                       __ATOMIC_RELAXED, __HIP_MEMORY_SCOPE_AGENT);
                if ((unsigned)(u0 & 0xFFFFFFFFu) != 0xFFFFFFFFu &&
                    (unsigned)(u0 >> 32)        != 0xFFFFFFFFu &&
                    (unsigned)(u1 & 0xFFFFFFFFu) != 0xFFFFFFFFu &&
                    (unsigned)(u1 >> 32)        != 0xFFFFFFFFu) break;
                if (++guard > (1 << 22)) break;   // liveness valve
            }
            const int d0 = 4 * lane;
            float* dst = &hsh[w][(d0 >> 6) * 68 + (d0 & 63)];
            *(float4*)dst = make_float4(
                __uint_as_float((unsigned)(u0 & 0xFFFFFFFFu)),
                __uint_as_float((unsigned)(u0 >> 32)),
                __uint_as_float((unsigned)(u1 & 0xFFFFFFFFu)),
                __uint_as_float((unsigned)(u1 >> 32)));
            asm volatile("s_waitcnt lgkmcnt(0)" ::: "memory");
            __builtin_amdgcn_sched_barrier(0);
            const float* src = &hsh[w][kq * 68];
#pragma unroll
            for (int c = 0; c < 16; ++c) {
                float ha[4];
                *(float4*)ha = *(const float4*)(src + 4 * c);
#pragma unroll
                for (int i = 0; i < 4; ++i) {
                    float4 wv = (c < 7) ? wreg[c * 4 + i] : wlds[(c - 7) * 4 + i][tid];
                    acc.x = fmaf(wv.x, ha[i], acc.x);
                    acc.y = fmaf(wv.y, ha[i], acc.y);
                    acc.z = fmaf(wv.z, ha[i], acc.z);
                    acc.w = fmaf(wv.w, ha[i], acc.w);
                }
            }
        }
        if (kq == 0) {
            acc.x += pre.x + breg.x; acc.y += pre.y + breg.y;
            acc.z += pre.z + breg.z; acc.w += pre.w + breg.w;
        }
#pragma unroll
        for (int off = 1; off <= 2; off <<= 1) {
            acc.x += __shfl_xor(acc.x, off);
            acc.y += __shfl_xor(acc.y, off);
            acc.z += __shfl_xor(acc.z, off);
            acc.w += __shfl_xor(acc.w, off);
        }
        float ig = sigm(acc.x), fg = sigm(acc.y), gt = tanhf(acc.z), og = sigm(acc.w);
        creg = fg * creg + ig * gt;
        float hn = og * tanhf(creg);
        if (kq == 0)
            __hip_atomic_store(hdir + ((size_t)b * 512 + t) * 256 + j0 + j, hn,
                               __ATOMIC_RELAXED, __HIP_MEMORY_SCOPE_AGENT);
    }
}

// ---------------------------------------------------------------------------
// K3: emissions  em[b][t][k] = hcat . W_clf[k] + b_clf[k]
// ---------------------------------------------------------------------------
__global__ __launch_bounds__(256) void k_em(const float* __restrict__ hf,
                                            const float* __restrict__ hb,
                                            const float* __restrict__ Wclf,
                                            const float* __restrict__ bclf,
                                            const int* __restrict__ lengths,
                                            float* __restrict__ em) {
    extern __shared__ float4 wc4[];   // [128][32]: wc4[jq*32+ko] = Wclf[ko][4jq..+3]
    const int tid = threadIdx.x;
    for (int idx = tid; idx < 4096; idx += 256) {
        int jq = idx >> 5, ko = idx & 31;
        wc4[idx] = *(const float4*)(Wclf + (size_t)ko * 512 + jq * 4);
    }
    __syncthreads();
    const int r = tid >> 5, ko = tid & 31;
    const int m = blockIdx.x * 8 + r;
    const int b = m >> 9, t = m & 511;
    const int len = lengths[b];
    const int rev = (t < len) ? (len - 1 - t) : t;
    const float* hfr = hf + (size_t)m * 256;
    const float* hbr = hb + (size_t)(b * 512 + rev) * 256;
    float acc = bclf[ko];
#pragma unroll 4
    for (int jq = 0; jq < 64; ++jq) {
        float4 h4 = *(const float4*)(hfr + jq * 4);
        float4 ww = wc4[jq * 32 + ko];
        acc += h4.x * ww.x + h4.y * ww.y + h4.z * ww.z + h4.w * ww.w;
    }
#pragma unroll 4
    for (int jq = 0; jq < 64; ++jq) {
        float4 h4 = *(const float4*)(hbr + jq * 4);
        float4 ww = wc4[(64 + jq) * 32 + ko];
        acc += h4.x * ww.x + h4.y * ww.y + h4.z * ww.z + h4.w * ww.w;
    }
    em[(size_t)m * 32 + ko] = acc;
}

// ---------------------------------------------------------------------------
// K4: CRF forward (logZ, num) and Viterbi (+backtrace) — WAVE-SYNC version
// (R10-verified). Single wave64 block; DS FIFO order replaces barriers;
// emb row t+1 prefetched during step t.
// ---------------------------------------------------------------------------
__global__ __launch_bounds__(64) void k_crfvit(const float* __restrict__ em,
                                               const int* __restrict__ targets,
                                               const int* __restrict__ lengths,
                                               const float* __restrict__ start_t,
                                               const float* __restrict__ end_t,
                                               const float* __restrict__ trans,
                                               float* __restrict__ numv,
                                               float* __restrict__ logZv,
                                               float* __restrict__ out) {
    __shared__ float trans_s[32][33];
    __shared__ float vec[32];
    __shared__ unsigned char hist[511 * 32];
    const int tid = threadIdx.x;
    const int b = blockIdx.x & 31;
    const int mode = blockIdx.x >> 5;
    for (int idx = tid; idx < 1024; idx += 64) trans_s[idx >> 5][idx & 31] = trans[idx];
    const int len = lengths[b];
    const float* emb = em + (size_t)b * 512 * 32;
    const int k = tid & 31, half = tid >> 5;
    if (tid < 32) vec[tid] = start_t[tid] + emb[tid];
    // no barrier: single wave, DS FIFO order covers trans_s/vec init->use

    if (mode == 0) {
        float e_cur = emb[32 + k];            // row t=1, broadcast to both halves
        for (int t = 1; t < NT; ++t) {
            float e_next = (t + 1 < NT) ? emb[(t + 1) * 32 + k] : 0.f;
            bool mv = t < len;
            int kp0 = half * 16;
            float m = -1e30f;
#pragma unroll 4
            for (int i = 0; i < 16; ++i)
                m = fmaxf(m, vec[kp0 + i] + trans_s[kp0 + i][k]);
            float m2 = fmaxf(m, __shfl_xor(m, 32));
            float ssum = 0.f;
#pragma unroll 4
            for (int i = 0; i < 16; ++i)
                ssum += __expf(vec[kp0 + i] + trans_s[kp0 + i][k] - m2);
            ssum += __shfl_xor(ssum, 32);
            float anew = m2 + __logf(ssum) + e_cur;
            if (half == 0 && mv) vec[k] = anew;   // same-wave DS order: safe
            e_cur = e_next;
        }
        float val = (tid < 32) ? vec[tid] + end_t[tid] : -1e30f;
        float m = val;
#pragma unroll
        for (int off = 32; off >= 1; off >>= 1) m = fmaxf(m, __shfl_xor(m, off));
        float e = (tid < 32) ? __expf(val - m) : 0.f;
#pragma unroll
        for (int off = 32; off >= 1; off >>= 1) e += __shfl_xor(e, off);
        if (tid == 0) logZv[b] = m + __logf(e);
        // numerator
        const int* tg = targets + b * 512;
        float partial = 0.f;
        for (int t = 1 + tid; t < NT; t += 64) {
            if (t < len) {
                int y0 = tg[t - 1], y1 = tg[t];
                partial += trans_s[y0][y1] + emb[t * 32 + y1];
            }
        }
#pragma unroll
        for (int off = 32; off >= 1; off >>= 1) partial += __shfl_xor(partial, off);
        if (tid == 0) {
            int y00 = tg[0];
            int yl = tg[len - 1];
            numv[b] = partial + start_t[y00] + emb[y00] + end_t[yl];
        }
    } else {
        float e_cur = emb[32 + k];
        for (int t = 1; t < NT; ++t) {
            float e_next = (t + 1 < NT) ? emb[(t + 1) * 32 + k] : 0.f;
            bool mv = t < len;
            int kp0 = half * 16;
            float e = e_cur;
            float m = -1e30f; int mi = kp0;
#pragma unroll 4
            for (int i = 0; i < 16; ++i) {
                float v = (vec[kp0 + i] + trans_s[kp0 + i][k]) + e;
                if (v > m) { m = v; mi = kp0 + i; }
            }
            float mo = __shfl_xor(m, 32);
            int io = __shfl_xor(mi, 32);
            float mlow = half ? mo : m;   int ilow = half ? io : mi;
            float mhigh = half ? m : mo;  int ihigh = half ? mi : io;
            float bm; int bi;
            if (mhigh > mlow) { bm = mhigh; bi = ihigh; } else { bm = mlow; bi = ilow; }
            if (half == 0) {
                hist[(t - 1) * 32 + k] = (unsigned char)(mv ? bi : k);
                if (mv) vec[k] = bm;              // same-wave DS order: safe
            }
            e_cur = e_next;
        }
        float val = (tid < 32) ? vec[tid] + end_t[tid] : -1e30f;
        int idx = (tid < 32) ? tid : 63;
#pragma unroll
        for (int off = 32; off >= 1; off >>= 1) {
            float vo = __shfl_xor(val, off);
            int io = __shfl_xor(idx, off);
            if (vo > val || (vo == val && io < idx)) { val = vo; idx = io; }
        }
        int cur = idx;
        float* ob = out + 1 + (size_t)b * 512;
        if (tid == 0) ob[511] = (511 < len) ? (float)cur : 0.f;
        for (int t2 = 510; t2 >= 0; --t2) {
            cur = hist[t2 * 32 + cur];
            if (tid == 0) ob[t2] = (t2 < len) ? (float)cur : 0.f;
        }
    }
}

// ---------------------------------------------------------------------------
// K5: loss = -mean(num - logZ)
// ---------------------------------------------------------------------------
__global__ __launch_bounds__(64) void k_loss(const float* __restrict__ numv,
                                             const float* __restrict__ logZv,
                                             float* __restrict__ out) {
    int tid = threadIdx.x;
    float v = (tid < 32) ? (logZv[tid] - numv[tid]) : 0.f;
#pragma unroll
    for (int off = 32; off >= 1; off >>= 1) v += __shfl_xor(v, off);
    if (tid == 0) out[0] = v / 32.f;
}

// ---------------------------------------------------------------------------
extern "C" void kernel_launch(void* const* d_in, const int* in_sizes, int n_in,
                              void* d_out, int out_size, void* d_ws, size_t ws_size,
                              hipStream_t stream) {
    const float* x       = (const float*)d_in[0];
    const int*   lengths = (const int*)d_in[1];
    // d_in[2] = mask (recomputed from lengths)
    const int*   targets = (const int*)d_in[3];
    const float* W_ih_f  = (const float*)d_in[4];
    const float* W_hh_f  = (const float*)d_in[5];
    const float* b_f     = (const float*)d_in[6];
    const float* W_ih_b  = (const float*)d_in[7];
    const float* W_hh_b  = (const float*)d_in[8];
    const float* b_b     = (const float*)d_in[9];
    const float* W_clf   = (const float*)d_in[10];
    const float* b_clf   = (const float*)d_in[11];
    const float* start_t = (const float*)d_in[12];
    const float* end_t   = (const float*)d_in[13];
    const float* trans   = (const float*)d_in[14];
    float* out = (float*)d_out;
    float* ws = (float*)d_ws;

    float* C     = ws;                                   // 16384*2048
    float* h_f   = C + (size_t)16384 * 2048;             // 32*512*256
    float* h_b   = h_f + (size_t)32 * 512 * 256;         // 32*512*256
    float* em    = h_b + (size_t)32 * 512 * 256;         // 32*512*32
    float4* Wt4  = (float4*)(em + (size_t)32 * 512 * 32);// 131072 float4
    float* numv  = (float*)(Wt4 + 131072);               // 32
    float* logZv = numv + 32;                            // 32

    // Re-poison h buffers with the sentinel bit pattern every launch
    // (graph-replay safe: per-iteration reset of the data-flags).
    hipMemsetAsync(h_f, 0xFF, (size_t)2 * 32 * 512 * 256 * sizeof(float), stream);
    k_wt4<<<512, 256, 0, stream>>>(W_hh_f, W_hh_b, Wt4);
    k_sgemm<<<dim3(16, 128), 256, 0, stream>>>(x, W_ih_f, W_ih_b, C);
    k_lstm6<<<256, 256, 0, stream>>>(C, Wt4, b_f, b_b, lengths, h_f, h_b);
    k_em<<<2048, 256, 65536, stream>>>(h_f, h_b, W_clf, b_clf, lengths, em);
    k_crfvit<<<64, 64, 0, stream>>>(em, targets, lengths, start_t, end_t, trans, numv, logZv, out);
    k_loss<<<1, 64, 0, stream>>>(numv, logZv, out);
}